// Round 3
// baseline (64.796 us; speedup 1.0000x reference)
//
#include <hip/hip_runtime.h>

#define BB 384   // batch
#define DD 128   // embedding dim
#define NI 3     // number of losses
#define SS 25    // seq len in target
#define GRID (NI * BB)
#define SCALE 1048576.0f   // 2^20 fixed-point for deterministic float accumulation

// Workspace accumulator layout (zeroed via hipMemsetAsync each call):
//   acc[0..2]  : fixed-point totals per i      (unsigned long long)
//   acc[3..5]  : triplet counts per i          (unsigned long long)
//   acc[6]     : done-counter (as unsigned int in low word)
__global__ __launch_bounds__(384) void fused_kernel(
    const float* __restrict__ vr,          // [NI, BB, DD]
    const float* __restrict__ target,      // [BB, SS, NI]
    const int*   __restrict__ label_item,  // [BB]
    unsigned long long* __restrict__ acc,
    float* __restrict__ out)               // [4]
{
    const int blk  = blockIdx.x;           // 0 .. GRID-1
    const int i    = blk / BB;
    const int a    = blk % BB;
    const int t    = threadIdx.x;          // 0 .. 383
    const int lane = t & 63;
    const int wid  = t >> 6;               // 0 .. 5

    __shared__ float ax[DD];               // anchor raw row
    __shared__ float aas;                  // ||x_a||^2
    __shared__ float labs[BB];
    __shared__ float dp_list[BB];
    __shared__ float dn_list[BB];
    __shared__ int   wp[6], wn[6];
    __shared__ float rf[6];
    __shared__ int   ri[6];

    // anchor raw row -> LDS (wave 0 threads 0..31, float4)
    const float* xa = vr + ((size_t)i * BB + a) * DD;
    if (t < DD / 4) ((float4*)ax)[t] = ((const float4*)xa)[t];

    // wave 0 computes ||x_a||^2 (in-wave ordering guarantees ax is written)
    if (wid == 0) {
        float v0 = ax[lane], v1 = ax[lane + 64];
        float s  = v0 * v0 + v1 * v1;
        #pragma unroll
        for (int off = 32; off > 0; off >>= 1) s += __shfl_down(s, off, 64);
        if (lane == 0) aas = s;
    }

    // own-row label
    float lt;
    if (i < 2) {
        lt = (float)label_item[t];
    } else {
        float m = 0.0f;
        const float* tp = target + (size_t)t * SS * NI + 2;
        #pragma unroll
        for (int s = 0; s < SS; ++s) m += tp[s * NI];
        lt = m / (float)SS;
    }
    labs[t] = lt;
    __syncthreads();

    // positive / negative classification + stream-compaction offsets
    const float la   = labs[a];
    const bool isPos = (lt == la) && (t != a);
    const bool isNeg = (lt != la);
    const unsigned long long mp = __ballot(isPos);
    const unsigned long long mn = __ballot(isNeg);
    const unsigned long long lowmask =
        (lane == 0) ? 0ull : (~0ull >> (64 - lane));
    const int rp = __popcll(mp & lowmask);
    const int rn = __popcll(mn & lowmask);
    if (lane == 0) { wp[wid] = __popcll(mp); wn[wid] = __popcll(mn); }
    __syncthreads();
    int posOff = 0, negOff = 0, P = 0, Nn = 0;
    #pragma unroll
    for (int w = 0; w < 6; ++w) {
        if (w < wid) { posOff += wp[w]; negOff += wn[w]; }
        P  += wp[w];
        Nn += wn[w];
    }

    if (P > 0) {   // block-uniform branch (i=2 blocks exit: continuous labels)
        // dist(a, t): fused dot + own-row squared norm, vectorized
        const float4* xb = (const float4*)(vr + ((size_t)i * BB + t) * DD);
        float ab = 0.0f, bb = 0.0f;
        #pragma unroll 8
        for (int k = 0; k < DD / 4; ++k) {
            const float4 b  = xb[k];
            const float4 av = ((const float4*)ax)[k];
            ab = fmaf(av.x, b.x, ab); bb = fmaf(b.x, b.x, bb);
            ab = fmaf(av.y, b.y, ab); bb = fmaf(b.y, b.y, bb);
            ab = fmaf(av.z, b.z, ab); bb = fmaf(b.z, b.z, bb);
            ab = fmaf(av.w, b.w, ab); bb = fmaf(b.w, b.w, bb);
        }
        const float aa   = aas;
        const float inva = 1.0f / fmaxf(sqrtf(aa), 1e-12f);
        const float invb = 1.0f / fmaxf(sqrtf(bb), 1e-12f);
        const float d2 = aa * inva * inva + bb * invb * invb
                         - 2.0f * ab * inva * invb;
        const float d  = sqrtf(fmaxf(d2, 0.0f));
        if (isPos) dp_list[posOff + rp] = d;
        if (isNeg) dn_list[negOff + rn] = d;
        __syncthreads();

        // pair sweep: thread owns compacted negative, loops over positives
        float tot = 0.0f;
        int   cnt = 0;
        if (t < Nn) {
            const float dn = dn_list[t];
            #pragma unroll 4
            for (int p = 0; p < P; ++p) {
                const float term = 1.0f - (dn - dp_list[p]);  // 1 - tm
                if (term > 0.0f && term < 1.0f) { cnt += 1; tot += term; }
            }
        }
        #pragma unroll
        for (int off = 32; off > 0; off >>= 1) {
            tot += __shfl_down(tot, off, 64);
            cnt += __shfl_down(cnt, off, 64);
        }
        if (lane == 0) { rf[wid] = tot; ri[wid] = cnt; }
        __syncthreads();
        if (t == 0) {
            float T = 0.0f; int C = 0;
            #pragma unroll
            for (int w = 0; w < 6; ++w) { T += rf[w]; C += ri[w]; }
            if (C > 0) {
                atomicAdd(&acc[i],      (unsigned long long)(T * SCALE + 0.5f));
                atomicAdd(&acc[NI + i], (unsigned long long)C);
            }
        }
    }

    // last-block-done finalize
    if (t == 0) {
        __threadfence();
        unsigned int old = atomicAdd((unsigned int*)&acc[2 * NI], 1u);
        if (old == (unsigned int)(GRID - 1)) {
            float lsum = 0.0f;
            #pragma unroll
            for (int ii = 0; ii < NI; ++ii) {
                unsigned long long T = atomicAdd(&acc[ii],      0ull);
                unsigned long long C = atomicAdd(&acc[NI + ii], 0ull);
                const float li = (C > 0)
                    ? ((float)T * (1.0f / SCALE)) / (float)C : 0.0f;
                out[1 + ii] = li;
                lsum += li;
            }
            out[0] = lsum;
        }
    }
}

extern "C" void kernel_launch(void* const* d_in, const int* in_sizes, int n_in,
                              void* d_out, int out_size, void* d_ws, size_t ws_size,
                              hipStream_t stream) {
    const float* vr         = (const float*)d_in[1];
    const float* target     = (const float*)d_in[2];
    const int*   label_item = (const int*)d_in[4];
    float* out = (float*)d_out;
    unsigned long long* acc = (unsigned long long*)d_ws;

    hipMemsetAsync(acc, 0, (2 * NI + 1) * sizeof(unsigned long long), stream);
    fused_kernel<<<GRID, 384, 0, stream>>>(vr, target, label_item, acc, out);
}

// Round 4
// 32.430 us; speedup vs baseline: 1.9980x; 1.9980x over previous
//
#include <hip/hip_runtime.h>

#define BB 384   // batch
#define DD 128   // embedding dim
#define NI 3     // number of losses
#define SS 25    // seq len in target
#define GRID (NI * BB)

// ---------------------------------------------------------------------------
// Kernel 1: per (i, anchor a) block. Labels + normalization fused. Blocks with
// no positives (all i=2 blocks: continuous labels) early-exit before any
// distance work. Each block writes (tot, cnt) partials to unique ws slots —
// plain stores, no atomics, no fences.
// ---------------------------------------------------------------------------
__global__ __launch_bounds__(384) void triplet_kernel(
    const float* __restrict__ vr,          // [NI, BB, DD]
    const float* __restrict__ target,      // [BB, SS, NI]
    const int*   __restrict__ label_item,  // [BB]
    float* __restrict__ tot_part,          // [GRID]
    int*   __restrict__ cnt_part)          // [GRID]
{
    const int blk  = blockIdx.x;           // 0 .. GRID-1
    const int i    = blk / BB;
    const int a    = blk % BB;
    const int t    = threadIdx.x;          // 0 .. 383
    const int lane = t & 63;
    const int wid  = t >> 6;               // 0 .. 5

    __shared__ float ax[DD];               // anchor raw row
    __shared__ float aas;                  // ||x_a||^2
    __shared__ float labs[BB];
    __shared__ float dp_list[BB];
    __shared__ float dn_list[BB];
    __shared__ int   wp[6], wn[6];
    __shared__ float rf[6];
    __shared__ int   ri[6];

    // own-row label first (gates classification for the whole block)
    float lt;
    if (i < 2) {
        lt = (float)label_item[t];
    } else {
        float m = 0.0f;
        const float* tp = target + (size_t)t * (SS * NI) + 2;
        #pragma unroll
        for (int s = 0; s < SS; ++s) m += tp[s * NI];
        lt = m / (float)SS;
    }

    // anchor raw row -> LDS (threads 0..31, i.e. wave 0, float4)
    const float* xa = vr + ((size_t)i * BB + a) * DD;
    if (t < DD / 4) ((float4*)ax)[t] = ((const float4*)xa)[t];

    // wave 0 computes ||x_a||^2 (intra-wave LDS ordering: writes above are
    // by lanes 0..31 of this same wave, in program order before these reads)
    if (wid == 0) {
        float v0 = ax[lane], v1 = ax[lane + 64];
        float s  = v0 * v0 + v1 * v1;
        #pragma unroll
        for (int off = 32; off > 0; off >>= 1) s += __shfl_down(s, off, 64);
        if (lane == 0) aas = s;
    }

    labs[t] = lt;
    __syncthreads();

    // classify + stream-compaction offsets
    const float la   = labs[a];
    const bool isPos = (lt == la) && (t != a);
    const bool isNeg = (lt != la);
    const unsigned long long mp = __ballot(isPos);
    const unsigned long long mn = __ballot(isNeg);
    const unsigned long long lowmask =
        (lane == 0) ? 0ull : (~0ull >> (64 - lane));
    const int rp = __popcll(mp & lowmask);
    const int rn = __popcll(mn & lowmask);
    if (lane == 0) { wp[wid] = __popcll(mp); wn[wid] = __popcll(mn); }
    __syncthreads();
    int posOff = 0, negOff = 0, P = 0, Nn = 0;
    #pragma unroll
    for (int w = 0; w < 6; ++w) {
        if (w < wid) { posOff += wp[w]; negOff += wn[w]; }
        P  += wp[w];
        Nn += wn[w];
    }

    if (P > 0) {   // block-uniform; i=2 blocks (continuous labels) skip all of this
        // dist(a, t): fused dot + own-row squared norm, vectorized
        const float4* xb = (const float4*)(vr + ((size_t)i * BB + t) * DD);
        float ab = 0.0f, bb = 0.0f;
        #pragma unroll 8
        for (int k = 0; k < DD / 4; ++k) {
            const float4 b  = xb[k];
            const float4 av = ((const float4*)ax)[k];
            ab = fmaf(av.x, b.x, ab); bb = fmaf(b.x, b.x, bb);
            ab = fmaf(av.y, b.y, ab); bb = fmaf(b.y, b.y, bb);
            ab = fmaf(av.z, b.z, ab); bb = fmaf(b.z, b.z, bb);
            ab = fmaf(av.w, b.w, ab); bb = fmaf(b.w, b.w, bb);
        }
        const float aa   = aas;
        const float inva = 1.0f / fmaxf(sqrtf(aa), 1e-12f);
        const float invb = 1.0f / fmaxf(sqrtf(bb), 1e-12f);
        const float d2 = aa * inva * inva + bb * invb * invb
                         - 2.0f * ab * inva * invb;
        const float d  = sqrtf(fmaxf(d2, 0.0f));
        if (isPos) dp_list[posOff + rp] = d;
        if (isNeg) dn_list[negOff + rn] = d;
        __syncthreads();

        // pair sweep: thread owns compacted negative, loops over positives
        float tot = 0.0f;
        int   cnt = 0;
        if (t < Nn) {
            const float dn = dn_list[t];
            #pragma unroll 4
            for (int p = 0; p < P; ++p) {
                const float term = 1.0f - (dn - dp_list[p]);  // 1 - (an - ap)
                if (term > 0.0f && term < 1.0f) { cnt += 1; tot += term; }
            }
        }
        #pragma unroll
        for (int off = 32; off > 0; off >>= 1) {
            tot += __shfl_down(tot, off, 64);
            cnt += __shfl_down(cnt, off, 64);
        }
        if (lane == 0) { rf[wid] = tot; ri[wid] = cnt; }
        __syncthreads();
        if (t == 0) {
            float T = 0.0f; int C = 0;
            #pragma unroll
            for (int w = 0; w < 6; ++w) { T += rf[w]; C += ri[w]; }
            tot_part[blk] = T;
            cnt_part[blk] = C;
        }
    } else {
        if (t == 0) { tot_part[blk] = 0.0f; cnt_part[blk] = 0; }
    }
}

// ---------------------------------------------------------------------------
// Kernel 2: reduce partials per i, compute losses, write [loss_sum, l0,l1,l2]
// 1 block x 384 threads. Fixed-order tree reduce -> deterministic.
// ---------------------------------------------------------------------------
__global__ __launch_bounds__(384) void finalize_kernel(
    const float* __restrict__ tot_part,
    const int*   __restrict__ cnt_part,
    float* __restrict__ out)
{
    __shared__ float rf[512];
    __shared__ int   ri[512];
    __shared__ float lsum;
    const int t = threadIdx.x;
    if (t == 0) lsum = 0.0f;
    for (int i = 0; i < NI; ++i) {
        rf[t] = tot_part[i * BB + t];
        ri[t] = cnt_part[i * BB + t];
        if (t < 128) { rf[384 + t] = 0.0f; ri[384 + t] = 0; }
        __syncthreads();
        #pragma unroll
        for (int off = 256; off > 0; off >>= 1) {
            if (t < off) { rf[t] += rf[t + off]; ri[t] += ri[t + off]; }
            __syncthreads();
        }
        if (t == 0) {
            const float li = (ri[0] > 0) ? (rf[0] / (float)ri[0]) : 0.0f;
            out[1 + i] = li;
            lsum += li;
        }
        __syncthreads();
    }
    if (t == 0) out[0] = lsum;
}

extern "C" void kernel_launch(void* const* d_in, const int* in_sizes, int n_in,
                              void* d_out, int out_size, void* d_ws, size_t ws_size,
                              hipStream_t stream) {
    const float* vr         = (const float*)d_in[1];
    const float* target     = (const float*)d_in[2];
    const int*   label_item = (const int*)d_in[4];
    float* out = (float*)d_out;

    float* tot_part = (float*)d_ws;            // GRID floats
    int*   cnt_part = (int*)(tot_part + GRID); // GRID ints

    triplet_kernel<<<GRID, 384, 0, stream>>>(vr, target, label_item,
                                             tot_part, cnt_part);
    finalize_kernel<<<1, 384, 0, stream>>>(tot_part, cnt_part, out);
}

// Round 5
// 30.802 us; speedup vs baseline: 2.1036x; 1.0528x over previous
//
#include <hip/hip_runtime.h>

#define BB 384   // batch
#define DD 128   // embedding dim
#define NI 3     // number of losses
#define SS 25    // seq len in target
#define GRID (NI * BB)

// ---------------------------------------------------------------------------
// Kernel 1: per (i, anchor a) block.
//  - i<2: int labels straight from label_item (no LDS exchange, no barrier)
//  - positives compacted into per-wave LDS segments (in-wave ballot rank only)
//  - negatives NOT compacted: each neg thread sweeps with its own d in-register
//  - P==0 blocks (all i=2 blocks, continuous labels) exit before distance work
// ---------------------------------------------------------------------------
__global__ __launch_bounds__(384) void triplet_kernel(
    const float* __restrict__ vr,          // [NI, BB, DD]
    const float* __restrict__ target,      // [BB, SS, NI]
    const int*   __restrict__ label_item,  // [BB]
    float* __restrict__ tot_part,          // [GRID]
    int*   __restrict__ cnt_part)          // [GRID]
{
    const int blk  = blockIdx.x;           // 0 .. GRID-1
    const int i    = blk / BB;
    const int a    = blk % BB;
    const int t    = threadIdx.x;          // 0 .. 383
    const int lane = t & 63;
    const int wid  = t >> 6;               // 0 .. 5

    __shared__ float ax[DD];               // anchor raw row
    __shared__ float aas;                  // ||x_a||^2
    __shared__ float dp_seg[6 * 64];       // per-wave positive-distance segments
    __shared__ int   wp[6];                // per-wave positive counts
    __shared__ float labs2[BB];            // i=2 only: per-row means
    __shared__ float rf[6];
    __shared__ int   ri[6];

    // anchor raw row -> LDS (lanes 0..31 of wave 0); wave 0 computes ||x_a||^2
    // (intra-wave LDS ordering: same-wave writes precede same-wave reads)
    const float* xa = vr + ((size_t)i * BB + a) * DD;
    if (t < DD / 4) ((float4*)ax)[t] = ((const float4*)xa)[t];
    if (wid == 0) {
        float v0 = ax[lane], v1 = ax[lane + 64];
        float s  = v0 * v0 + v1 * v1;
        #pragma unroll
        for (int off = 32; off > 0; off >>= 1) s += __shfl_down(s, off, 64);
        if (lane == 0) aas = s;
    }

    // classification (registers only for i<2; LDS exchange only for i=2)
    bool isPos, isNeg;
    if (i < 2) {
        const int li_t = label_item[t];
        const int li_a = label_item[a];    // uniform address -> scalar load
        isPos = (li_t == li_a) && (t != a);
        isNeg = (li_t != li_a);
    } else {
        float m = 0.0f;
        const float* tp = target + (size_t)t * (SS * NI) + 2;
        #pragma unroll
        for (int s = 0; s < SS; ++s) m += tp[s * NI];
        m *= (1.0f / (float)SS);
        labs2[t] = m;
        __syncthreads();
        const float la = labs2[a];
        isPos = (m == la) && (t != a);
        isNeg = (m != la);
    }

    const unsigned long long mp = __ballot(isPos);
    const unsigned long long lowmask =
        (lane == 0) ? 0ull : (~0ull >> (64 - lane));
    const int rp = __popcll(mp & lowmask);   // in-wave rank among positives
    if (lane == 0) wp[wid] = __popcll(mp);
    __syncthreads();                         // ax, aas, wp (and labs2) visible

    int P = 0;
    #pragma unroll
    for (int w = 0; w < 6; ++w) P += wp[w];
    if (P == 0) {                            // block-uniform early exit
        if (t == 0) { tot_part[blk] = 0.0f; cnt_part[blk] = 0; }
        return;
    }

    // dist(a, t): fused dot + own-row squared norm, vectorized
    const float4* xb = (const float4*)(vr + ((size_t)i * BB + t) * DD);
    float ab = 0.0f, bb = 0.0f;
    #pragma unroll 8
    for (int k = 0; k < DD / 4; ++k) {
        const float4 b  = xb[k];
        const float4 av = ((const float4*)ax)[k];
        ab = fmaf(av.x, b.x, ab); bb = fmaf(b.x, b.x, bb);
        ab = fmaf(av.y, b.y, ab); bb = fmaf(b.y, b.y, bb);
        ab = fmaf(av.z, b.z, ab); bb = fmaf(b.z, b.z, bb);
        ab = fmaf(av.w, b.w, ab); bb = fmaf(b.w, b.w, bb);
    }
    const float aa   = aas;
    const float inva = 1.0f / fmaxf(sqrtf(aa), 1e-12f);
    const float invb = 1.0f / fmaxf(sqrtf(bb), 1e-12f);
    const float d2 = aa * inva * inva + bb * invb * invb
                     - 2.0f * ab * inva * invb;
    const float d  = sqrtf(fmaxf(d2, 0.0f));
    if (isPos) dp_seg[(wid << 6) + rp] = d;
    __syncthreads();

    // sweep: each NEGATIVE thread (d in register) loops over compacted positives
    float tot = 0.0f;
    int   cnt = 0;
    if (isNeg) {
        #pragma unroll
        for (int w = 0; w < 6; ++w) {
            const int    Pw  = wp[w];
            const float* seg = dp_seg + (w << 6);
            #pragma unroll 4
            for (int p = 0; p < Pw; ++p) {
                const float term = 1.0f - (d - seg[p]);   // 1 - (an - ap)
                if (term > 0.0f && term < 1.0f) { cnt += 1; tot += term; }
            }
        }
    }
    #pragma unroll
    for (int off = 32; off > 0; off >>= 1) {
        tot += __shfl_down(tot, off, 64);
        cnt += __shfl_down(cnt, off, 64);
    }
    if (lane == 0) { rf[wid] = tot; ri[wid] = cnt; }
    __syncthreads();
    if (t == 0) {
        float T = 0.0f; int C = 0;
        #pragma unroll
        for (int w = 0; w < 6; ++w) { T += rf[w]; C += ri[w]; }
        tot_part[blk] = T;
        cnt_part[blk] = C;
    }
}

// ---------------------------------------------------------------------------
// Kernel 2: shuffle-based reduce of 3x384 partials, 1 barrier, 4 outputs.
// ---------------------------------------------------------------------------
__global__ __launch_bounds__(384) void finalize_kernel(
    const float* __restrict__ tot_part,
    const int*   __restrict__ cnt_part,
    float* __restrict__ out)
{
    const int t    = threadIdx.x;
    const int lane = t & 63;
    const int wid  = t >> 6;
    __shared__ float rf[18];
    __shared__ int   ri[18];

    float t0 = tot_part[t], t1 = tot_part[BB + t], t2 = tot_part[2 * BB + t];
    int   c0 = cnt_part[t], c1 = cnt_part[BB + t], c2 = cnt_part[2 * BB + t];
    #pragma unroll
    for (int off = 32; off > 0; off >>= 1) {
        t0 += __shfl_down(t0, off, 64);
        t1 += __shfl_down(t1, off, 64);
        t2 += __shfl_down(t2, off, 64);
        c0 += __shfl_down(c0, off, 64);
        c1 += __shfl_down(c1, off, 64);
        c2 += __shfl_down(c2, off, 64);
    }
    if (lane == 0) {
        rf[wid * 3 + 0] = t0; rf[wid * 3 + 1] = t1; rf[wid * 3 + 2] = t2;
        ri[wid * 3 + 0] = c0; ri[wid * 3 + 1] = c1; ri[wid * 3 + 2] = c2;
    }
    __syncthreads();
    if (t == 0) {
        float lsum = 0.0f;
        #pragma unroll
        for (int i = 0; i < NI; ++i) {
            float T = 0.0f; int C = 0;
            #pragma unroll
            for (int w = 0; w < 6; ++w) { T += rf[w * 3 + i]; C += ri[w * 3 + i]; }
            const float li = (C > 0) ? (T / (float)C) : 0.0f;
            out[1 + i] = li;
            lsum += li;
        }
        out[0] = lsum;
    }
}

extern "C" void kernel_launch(void* const* d_in, const int* in_sizes, int n_in,
                              void* d_out, int out_size, void* d_ws, size_t ws_size,
                              hipStream_t stream) {
    const float* vr         = (const float*)d_in[1];
    const float* target     = (const float*)d_in[2];
    const int*   label_item = (const int*)d_in[4];
    float* out = (float*)d_out;

    float* tot_part = (float*)d_ws;            // GRID floats
    int*   cnt_part = (int*)(tot_part + GRID); // GRID ints

    triplet_kernel<<<GRID, 384, 0, stream>>>(vr, target, label_item,
                                             tot_part, cnt_part);
    finalize_kernel<<<1, 384, 0, stream>>>(tot_part, cnt_part, out);
}

// Round 6
// 25.389 us; speedup vs baseline: 2.5521x; 1.2132x over previous
//
#include <hip/hip_runtime.h>

#define BB 384   // batch
#define DD 128   // embedding dim
#define NI 3     // number of losses
#define SS 25    // seq len in target
#define APB 4    // anchors per block
#define BPI (BB / APB)         // 96 blocks per i
#define GRID (NI * BPI)        // 288
#define PSTRIDE 128            // padded partial stride per i

// ---------------------------------------------------------------------------
// Kernel 1: per block = (i, 4 consecutive anchors). Each thread owns row t:
// loads it once from global, computes 4 dots against LDS-resident anchor rows.
// Anchor norms come free: thread t==a_k publishes its own-row norm.
// Block pre-sums its 4 anchors' (tot,cnt) into one partial slot.
// ---------------------------------------------------------------------------
__global__ __launch_bounds__(384) void triplet_kernel(
    const float* __restrict__ vr,          // [NI, BB, DD]
    const float* __restrict__ target,      // [BB, SS, NI]
    const int*   __restrict__ label_item,  // [BB]
    float* __restrict__ part_T,            // [NI * PSTRIDE]
    int*   __restrict__ part_C)            // [NI * PSTRIDE]
{
    const int blk  = blockIdx.x;           // 0 .. GRID-1
    const int i    = blk / BPI;
    const int b    = blk % BPI;
    const int a0   = b * APB;
    const int t    = threadIdx.x;          // 0 .. 383
    const int lane = t & 63;
    const int wid  = t >> 6;               // 0 .. 5

    __shared__ float ax[APB][DD];          // 4 anchor raw rows
    __shared__ float aas[APB];             // ||x_{a_k}||^2
    __shared__ float dp_seg[APB][BB];      // per-wave positive-dist segments
    __shared__ int   wp[6][APB];           // per-wave positive counts
    __shared__ float labs2[BB];            // i=2 only
    __shared__ float rf[6];
    __shared__ int   ri[6];

    // anchor rows -> LDS (threads 0..127 = waves 0-1, float4)
    if (t < APB * DD / 4) {
        const int k = t >> 5, c = t & 31;
        ((float4*)ax[k])[c] =
            ((const float4*)(vr + ((size_t)i * BB + a0 + k) * DD))[c];
    }

    // classification per anchor
    bool isPos[APB], isNeg[APB];
    if (i < 2) {
        const int li_t = label_item[t];
        #pragma unroll
        for (int k = 0; k < APB; ++k) {
            const int li_a = label_item[a0 + k];   // uniform -> scalar load
            isPos[k] = (li_t == li_a) && (t != a0 + k);
            isNeg[k] = (li_t != li_a);
        }
    } else {
        float m = 0.0f;
        const float* tp = target + (size_t)t * (SS * NI) + 2;
        #pragma unroll
        for (int s = 0; s < SS; ++s) m += tp[s * NI];
        m *= (1.0f / (float)SS);
        labs2[t] = m;
        __syncthreads();
        #pragma unroll
        for (int k = 0; k < APB; ++k) {
            const float la = labs2[a0 + k];
            isPos[k] = (m == la) && (t != a0 + k);
            isNeg[k] = (m != la);
        }
    }

    // in-wave compaction ranks per anchor
    int rp[APB];
    const unsigned long long lowmask =
        (lane == 0) ? 0ull : (~0ull >> (64 - lane));
    #pragma unroll
    for (int k = 0; k < APB; ++k) {
        const unsigned long long mpk = __ballot(isPos[k]);
        rp[k] = __popcll(mpk & lowmask);
        if (lane == 0) wp[wid][k] = __popcll(mpk);
    }
    __syncthreads();                       // B1: ax, wp (and labs2) visible

    int Pany = 0;
    #pragma unroll
    for (int k = 0; k < APB; ++k) {
        #pragma unroll
        for (int w = 0; w < 6; ++w) Pany += wp[w][k];
    }
    if (Pany == 0) {                       // block-uniform (all i=2 blocks a.s.)
        if (t == 0) { part_T[i * PSTRIDE + b] = 0.0f; part_C[i * PSTRIDE + b] = 0; }
        return;
    }

    // 4 dots + own-row squared norm; row loaded once from global
    const float4* xb = (const float4*)(vr + ((size_t)i * BB + t) * DD);
    float ab0 = 0.0f, ab1 = 0.0f, ab2 = 0.0f, ab3 = 0.0f, bb = 0.0f;
    #pragma unroll 4
    for (int c = 0; c < DD / 4; ++c) {
        const float4 bv  = xb[c];
        const float4 a0v = ((const float4*)ax[0])[c];
        const float4 a1v = ((const float4*)ax[1])[c];
        const float4 a2v = ((const float4*)ax[2])[c];
        const float4 a3v = ((const float4*)ax[3])[c];
        ab0 = fmaf(a0v.x, bv.x, ab0); ab0 = fmaf(a0v.y, bv.y, ab0);
        ab0 = fmaf(a0v.z, bv.z, ab0); ab0 = fmaf(a0v.w, bv.w, ab0);
        ab1 = fmaf(a1v.x, bv.x, ab1); ab1 = fmaf(a1v.y, bv.y, ab1);
        ab1 = fmaf(a1v.z, bv.z, ab1); ab1 = fmaf(a1v.w, bv.w, ab1);
        ab2 = fmaf(a2v.x, bv.x, ab2); ab2 = fmaf(a2v.y, bv.y, ab2);
        ab2 = fmaf(a2v.z, bv.z, ab2); ab2 = fmaf(a2v.w, bv.w, ab2);
        ab3 = fmaf(a3v.x, bv.x, ab3); ab3 = fmaf(a3v.y, bv.y, ab3);
        ab3 = fmaf(a3v.z, bv.z, ab3); ab3 = fmaf(a3v.w, bv.w, ab3);
        bb  = fmaf(bv.x,  bv.x, bb ); bb  = fmaf(bv.y,  bv.y, bb );
        bb  = fmaf(bv.z,  bv.z, bb ); bb  = fmaf(bv.w,  bv.w, bb );
    }
    // anchor a_k IS row a_k: its thread publishes bb as the anchor norm
    if (t >= a0 && t < a0 + APB) aas[t - a0] = bb;
    __syncthreads();                       // B2: aas visible

    const float invb   = 1.0f / fmaxf(sqrtf(bb), 1e-12f);
    const float bbterm = bb * invb * invb;
    const float ab[APB] = { ab0, ab1, ab2, ab3 };
    float d[APB];
    #pragma unroll
    for (int k = 0; k < APB; ++k) {
        const float aak  = aas[k];
        const float inva = 1.0f / fmaxf(sqrtf(aak), 1e-12f);
        const float d2   = aak * inva * inva + bbterm
                           - 2.0f * ab[k] * inva * invb;
        d[k] = sqrtf(fmaxf(d2, 0.0f));
        if (isPos[k]) dp_seg[k][(wid << 6) + rp[k]] = d[k];
    }
    __syncthreads();                       // B3: dp_seg visible

    // sweep: each negative thread loops over compacted positives, all 4 anchors
    float tot = 0.0f;
    int   cnt = 0;
    #pragma unroll
    for (int k = 0; k < APB; ++k) {
        if (isNeg[k]) {
            const float dk = d[k];
            #pragma unroll
            for (int w = 0; w < 6; ++w) {
                const int    Pw  = wp[w][k];
                const float* seg = &dp_seg[k][w << 6];
                #pragma unroll 4
                for (int p = 0; p < Pw; ++p) {
                    const float term = 1.0f - (dk - seg[p]);
                    if (term > 0.0f && term < 1.0f) { cnt += 1; tot += term; }
                }
            }
        }
    }
    #pragma unroll
    for (int off = 32; off > 0; off >>= 1) {
        tot += __shfl_down(tot, off, 64);
        cnt += __shfl_down(cnt, off, 64);
    }
    if (lane == 0) { rf[wid] = tot; ri[wid] = cnt; }
    __syncthreads();
    if (t == 0) {
        float T = 0.0f; int C = 0;
        #pragma unroll
        for (int w = 0; w < 6; ++w) { T += rf[w]; C += ri[w]; }
        part_T[i * PSTRIDE + b] = T;
        part_C[i * PSTRIDE + b] = C;
    }
}

// ---------------------------------------------------------------------------
// Kernel 2: 384 threads; waves (2k,2k+1) reduce loss k. 1 barrier.
// ---------------------------------------------------------------------------
__global__ __launch_bounds__(384) void finalize_kernel(
    const float* __restrict__ part_T,
    const int*   __restrict__ part_C,
    float* __restrict__ out)
{
    const int t    = threadIdx.x;
    const int lane = t & 63;
    const int wid  = t >> 6;
    const int i    = t >> 7;       // 128-thread group per loss
    const int b    = t & 127;
    __shared__ float rf[6];
    __shared__ int   ri[6];

    float T = (b < BPI) ? part_T[i * PSTRIDE + b] : 0.0f;
    int   C = (b < BPI) ? part_C[i * PSTRIDE + b] : 0;
    #pragma unroll
    for (int off = 32; off > 0; off >>= 1) {
        T += __shfl_down(T, off, 64);
        C += __shfl_down(C, off, 64);
    }
    if (lane == 0) { rf[wid] = T; ri[wid] = C; }
    __syncthreads();
    if (t == 0) {
        float lsum = 0.0f;
        #pragma unroll
        for (int ii = 0; ii < NI; ++ii) {
            const float Ti = rf[2 * ii] + rf[2 * ii + 1];
            const int   Ci = ri[2 * ii] + ri[2 * ii + 1];
            const float li = (Ci > 0) ? (Ti / (float)Ci) : 0.0f;
            out[1 + ii] = li;
            lsum += li;
        }
        out[0] = lsum;
    }
}

extern "C" void kernel_launch(void* const* d_in, const int* in_sizes, int n_in,
                              void* d_out, int out_size, void* d_ws, size_t ws_size,
                              hipStream_t stream) {
    const float* vr         = (const float*)d_in[1];
    const float* target     = (const float*)d_in[2];
    const int*   label_item = (const int*)d_in[4];
    float* out = (float*)d_out;

    float* part_T = (float*)d_ws;                  // NI*PSTRIDE floats
    int*   part_C = (int*)(part_T + NI * PSTRIDE); // NI*PSTRIDE ints

    triplet_kernel<<<GRID, 384, 0, stream>>>(vr, target, label_item,
                                             part_T, part_C);
    finalize_kernel<<<1, 384, 0, stream>>>(part_T, part_C, out);
}